// Round 8
// baseline (138.445 us; speedup 1.0000x reference)
//
#include <hip/hip_runtime.h>
#include <hip/hip_bf16.h>

#define NH 16
#define DH 64
#define DM 1024
#define NC 2048
#define MROWS 4096
#define KVT 32

#define SCALE_Q 0.180336880f   // 0.125 * log2(e): softmax done in 2^x domain

typedef __attribute__((ext_vector_type(8))) short short8;
typedef __attribute__((ext_vector_type(4))) float f32x4;
typedef __attribute__((ext_vector_type(16))) float f32x16;
typedef __attribute__((ext_vector_type(4))) unsigned int uint4e;

__device__ __forceinline__ unsigned pkbf16(float a, float b) {
    unsigned r;
    asm("v_cvt_pk_bf16_f32 %0, %1, %2" : "=v"(r) : "v"(a), "v"(b));
    return r;
}
__device__ __forceinline__ unsigned short f2bf(float x) {
    return (unsigned short)(pkbf16(x, x) & 0xffffu);
}
__device__ __forceinline__ float exp2v(float x) {   // 2^x, v_exp_f32
    float r;
    asm("v_exp_f32 %0, %1" : "=v"(r) : "v"(x));
    return r;
}
__device__ __forceinline__ f32x16 fzero16() {
    f32x16 r;
    #pragma unroll
    for (int i = 0; i < 16; ++i) r[i] = 0.f;
    return r;
}
__device__ __forceinline__ short8 mk8(unsigned w0, unsigned w1, unsigned w2, unsigned w3) {
    uint4e u = {w0, w1, w2, w3};
    return __builtin_bit_cast(short8, u);
}
// async global->LDS, 16B per lane; lds dest = wave-uniform base + lane*16 (HW)
__device__ __forceinline__ void gload16(const unsigned short* g, unsigned short* l) {
    __builtin_amdgcn_global_load_lds(
        (const __attribute__((address_space(1))) void*)g,
        (__attribute__((address_space(3))) void*)l, 16, 0, 0);
}

// ---------------------------------------------------------------------------
// fp32 -> bf16 elementwise convert (8 elems/thread)
// ---------------------------------------------------------------------------
__global__ __launch_bounds__(256) void cvt_x(const float* __restrict__ in,
                                             unsigned short* __restrict__ out, int n8)
{
    int i = blockIdx.x * 256 + threadIdx.x;
    if (i >= n8) return;
    const float4 a = ((const float4*)in)[i * 2];
    const float4 b = ((const float4*)in)[i * 2 + 1];
    uint4e u = {pkbf16(a.x, a.y), pkbf16(a.z, a.w), pkbf16(b.x, b.y), pkbf16(b.z, b.w)};
    ((uint4e*)out)[i] = u;
}

// ---------------------------------------------------------------------------
// All 4 weights: W[K][N] fp32 -> Wt[N][K] bf16, fused (blockIdx.z = which W)
// ---------------------------------------------------------------------------
__global__ __launch_bounds__(256) void cvt_w4(const float* __restrict__ W0,
                                              const float* __restrict__ W1,
                                              const float* __restrict__ W2,
                                              const float* __restrict__ W3,
                                              unsigned short* __restrict__ Wt4)
{
    __shared__ unsigned short T[64][72];
    const int z = blockIdx.z;
    const float* W = (z == 0) ? W0 : (z == 1) ? W1 : (z == 2) ? W2 : W3;
    unsigned short* Wt = Wt4 + (size_t)z * DM * DM;
    const int t = threadIdx.x;
    const int r = t >> 2, s = t & 3;
    const int bi = blockIdx.y;
    const int bj = blockIdx.x;
    const float* src = W + (size_t)(bi * 64 + r) * DM + bj * 64 + s * 16;
    float4 f0 = ((const float4*)src)[0];
    float4 f1 = ((const float4*)src)[1];
    float4 f2 = ((const float4*)src)[2];
    float4 f3 = ((const float4*)src)[3];
    uint2 u;
    u.x = pkbf16(f0.x, f0.y); u.y = pkbf16(f0.z, f0.w); *(uint2*)&T[r][s * 16]      = u;
    u.x = pkbf16(f1.x, f1.y); u.y = pkbf16(f1.z, f1.w); *(uint2*)&T[r][s * 16 + 4]  = u;
    u.x = pkbf16(f2.x, f2.y); u.y = pkbf16(f2.z, f2.w); *(uint2*)&T[r][s * 16 + 8]  = u;
    u.x = pkbf16(f3.x, f3.y); u.y = pkbf16(f3.z, f3.w); *(uint2*)&T[r][s * 16 + 12] = u;
    __syncthreads();
    unsigned short vals[16];
    #pragma unroll
    for (int j = 0; j < 16; ++j) vals[j] = T[s * 16 + j][r];
    unsigned short* dst = Wt + (size_t)(bj * 64 + r) * DM + bi * 64 + s * 16;
    *(short8*)(dst)     = *(short8*)&vals[0];
    *(short8*)(dst + 8) = *(short8*)&vals[8];
}

// ---------------------------------------------------------------------------
// Fused QKV projection (m97 structure): 128x128 tile, BK=32, 4 waves,
// global_load_lds width-16 staging into LINEAR LDS [128][32] shorts.
// Q pre-scaled by SCALE_Q. V segment written TRANSPOSED to Vt[bh][d][n].
// ---------------------------------------------------------------------------
__global__ __launch_bounds__(256) void gemm_qkv(const unsigned short* __restrict__ A,
                                                const unsigned short* __restrict__ Bt,
                                                const float* __restrict__ bq,
                                                const float* __restrict__ bk,
                                                const float* __restrict__ bv,
                                                unsigned short* __restrict__ Out)
{
    __shared__ unsigned short As[128 * 32];
    __shared__ unsigned short Bs[128 * 32];
    const int t  = threadIdx.x;
    const int w  = t >> 6, l = t & 63;
    const int wr = w >> 1, wc = w & 1;
    const int m0 = blockIdx.y << 7;
    const int n0 = blockIdx.x << 7;

    f32x4 acc[4][4] = {};
    const int nkt = DM >> 5;
    for (int kt = 0; kt < nkt; ++kt) {
        #pragma unroll
        for (int j = 0; j < 2; ++j) {
            const int c0 = j * 256 + w * 64;          // wave-uniform chunk base
            const int cc = c0 + l;                    // per-lane chunk
            const int row = cc >> 2, qq = cc & 3;
            gload16(A  + (size_t)(m0 + row) * DM + kt * 32 + qq * 8, &As[c0 * 8]);
            gload16(Bt + (size_t)(n0 + row) * DM + kt * 32 + qq * 8, &Bs[c0 * 8]);
        }
        __syncthreads();
        short8 af[4], bf_[4];
        #pragma unroll
        for (int mi = 0; mi < 4; ++mi)
            af[mi] = *(short8*)&As[(wr * 64 + mi * 16 + (l & 15)) * 32 + (l >> 4) * 8];
        #pragma unroll
        for (int ni = 0; ni < 4; ++ni)
            bf_[ni] = *(short8*)&Bs[(wc * 64 + ni * 16 + (l & 15)) * 32 + (l >> 4) * 8];
        #pragma unroll
        for (int mi = 0; mi < 4; ++mi)
            #pragma unroll
            for (int ni = 0; ni < 4; ++ni)
                acc[mi][ni] = __builtin_amdgcn_mfma_f32_16x16x32_bf16(
                                  af[mi], bf_[ni], acc[mi][ni], 0, 0, 0);
        __syncthreads();
    }

    const int seg = n0 >> 10;
    const float* bias = (seg == 0) ? bq : (seg == 1) ? bk : bv;
    const float scale = (seg == 0) ? SCALE_Q : 1.0f;
    const int ncol0 = (n0 & 1023) + wc * 64;
    float bvv[4];
    #pragma unroll
    for (int ni = 0; ni < 4; ++ni)
        bvv[ni] = bias[ncol0 + ni * 16 + (l & 15)];

    if (seg == 2) {
        // V: write transposed Vt[bh][d][n] (bh = b*16+h)
        unsigned short* vt = Out + 2 * (size_t)MROWS * DM;
        #pragma unroll
        for (int mi = 0; mi < 4; ++mi)
            #pragma unroll
            for (int ni = 0; ni < 4; ++ni) {
                const int gcol = ncol0 + ni * 16 + (l & 15);
                const int h_ = gcol >> 6, d_ = gcol & 63;
                #pragma unroll
                for (int r = 0; r < 4; ++r) {
                    const int grow = m0 + wr * 64 + mi * 16 + (l >> 4) * 4 + r;
                    const int b_ = grow >> 11, n_ = grow & 2047;
                    vt[(((size_t)b_ * 16 + h_) * 64 + d_) * NC + n_] =
                        f2bf(acc[mi][ni][r] + bvv[ni]);
                }
            }
    } else {
        unsigned short* C = Out + (size_t)seg * MROWS * DM;
        #pragma unroll
        for (int mi = 0; mi < 4; ++mi)
            #pragma unroll
            for (int ni = 0; ni < 4; ++ni) {
                const int gcol = ncol0 + ni * 16 + (l & 15);
                #pragma unroll
                for (int r = 0; r < 4; ++r) {
                    const int grow = m0 + wr * 64 + mi * 16 + (l >> 4) * 4 + r;
                    C[(size_t)grow * DM + gcol] = f2bf((acc[mi][ni][r] + bvv[ni]) * scale);
                }
            }
    }
}

// ---------------------------------------------------------------------------
// Output projection: 64x128 tile, gload_lds staging, fp32 out.
// ---------------------------------------------------------------------------
__global__ __launch_bounds__(256) void gemm_wo(const unsigned short* __restrict__ A,
                                               const unsigned short* __restrict__ Bt,
                                               float* __restrict__ C)
{
    __shared__ unsigned short As[64 * 32];
    __shared__ unsigned short Bs[128 * 32];
    const int t = threadIdx.x, w = t >> 6, l = t & 63;
    const int wr = w >> 1, wc = w & 1;
    const int m0 = blockIdx.y << 6;
    const int n0 = blockIdx.x << 7;

    f32x4 acc[2][4] = {};
    const int nkt = DM >> 5;
    for (int kt = 0; kt < nkt; ++kt) {
        {
            const int c0 = w * 64;
            const int cc = c0 + l;
            const int row = cc >> 2, qq = cc & 3;
            gload16(A + (size_t)(m0 + row) * DM + kt * 32 + qq * 8, &As[c0 * 8]);
        }
        #pragma unroll
        for (int j = 0; j < 2; ++j) {
            const int c0 = j * 256 + w * 64;
            const int cc = c0 + l;
            const int row = cc >> 2, qq = cc & 3;
            gload16(Bt + (size_t)(n0 + row) * DM + kt * 32 + qq * 8, &Bs[c0 * 8]);
        }
        __syncthreads();
        short8 af[2], bf_[4];
        #pragma unroll
        for (int mi = 0; mi < 2; ++mi)
            af[mi] = *(short8*)&As[(wr * 32 + mi * 16 + (l & 15)) * 32 + (l >> 4) * 8];
        #pragma unroll
        for (int ni = 0; ni < 4; ++ni)
            bf_[ni] = *(short8*)&Bs[(wc * 64 + ni * 16 + (l & 15)) * 32 + (l >> 4) * 8];
        #pragma unroll
        for (int mi = 0; mi < 2; ++mi)
            #pragma unroll
            for (int ni = 0; ni < 4; ++ni)
                acc[mi][ni] = __builtin_amdgcn_mfma_f32_16x16x32_bf16(
                                  af[mi], bf_[ni], acc[mi][ni], 0, 0, 0);
        __syncthreads();
    }
    #pragma unroll
    for (int mi = 0; mi < 2; ++mi)
        #pragma unroll
        for (int ni = 0; ni < 4; ++ni) {
            const int gcol = n0 + wc * 64 + ni * 16 + (l & 15);
            #pragma unroll
            for (int r = 0; r < 4; ++r) {
                const int grow = m0 + wr * 32 + mi * 16 + (l >> 4) * 4 + r;
                C[(size_t)grow * DM + gcol] = acc[mi][ni][r];
            }
        }
}

// ---------------------------------------------------------------------------
// Wave-independent bf16-MFMA flash attention. ONE wave per block, 2048 blocks
// (8 blocks/CU; LDS 16KB/block). Wave-private double-buffered K/V tiles staged
// by global_load_lds; sync by COUNTED s_waitcnt vmcnt(8) only — ZERO barriers.
// KVT=32: per iter 4 QK + 4 PV MFMA. K tile [32][128B] slot^=(row&7) swizzle,
// V tile [64][64B] slot^=(row&3) swizzle (both applied on DMA source).
// Softmax in 2^x domain, static diagonal mask, T13 defer-rescale, T1 swizzle.
// ---------------------------------------------------------------------------
__global__ __launch_bounds__(64, 2) void attn_wave(const unsigned short* __restrict__ Qg,
                                                   const unsigned short* __restrict__ Kg,
                                                   const unsigned short* __restrict__ Vtg,
                                                   unsigned short* __restrict__ Og)
{
    __shared__ unsigned short KS[2][2048];   // [buf][32 rows][8 slots x 8 sh]
    __shared__ unsigned short VS[2][2048];   // [buf][64 rows][4 slots x 8 sh]
    const int l   = threadIdx.x;
    const int l31 = l & 31;
    const int hi  = l >> 5;

    // T1 XCD-chunked swizzle: 2048 blocks, 8 XCDs -> 4 (b,h) x 64 q-tiles each
    const int f   = blockIdx.x;
    const int xcd = f & 7;
    const int pos = f >> 3;               // 0..255
    const int bh  = xcd * 4 + (pos >> 6);
    int qt = pos & 63;
    if ((pos >> 6) & 1) qt = 63 - qt;     // long/short causal pairing
    const int b = bh >> 4;
    const int h = bh & 15;

    const int qb = qt << 5;               // 32 q-rows per wave
    const size_t rb0 = (size_t)b * NC;
    const int hd = h * DH;

    // Q fragments (pre-scaled by 0.125*log2e in projection)
    const unsigned short* qp = Qg + (rb0 + qb + l31) * DM + hd + hi * 8;
    short8 fq[4];
    #pragma unroll
    for (int c = 0; c < 4; ++c)
        fq[c] = *(const short8*)(qp + c * 16);

    f32x16 o0 = fzero16(), o1 = fzero16();
    float mrun = -1e30f, lrun = 0.f;
    const bool bottom = (qb >= NC / 2);   // qt >= 32
    const int nkv = bottom ? (qt + 1) : 32;

    const unsigned short* Vbase = Vtg + (size_t)bh * 64 * NC;

    // stage one KV tile (4 K-DMA + 4 V-DMA, inverse swizzle on global source)
    auto stage = [&](int it, int buf) {
        const int kb = it * KVT;
        #pragma unroll
        for (int j = 0; j < 4; ++j) {
            const int pk  = j * 64 + l;                 // K chunk 0..255
            const int krow = pk >> 3, kslot = (pk & 7) ^ (krow & 7);
            gload16(Kg + (size_t)(rb0 + kb + krow) * DM + hd + kslot * 8,
                    &KS[buf][j * 512]);
            const int vrow = pk >> 2, vslot = (pk & 3) ^ (vrow & 3);
            gload16(Vbase + (size_t)vrow * NC + kb + vslot * 8,
                    &VS[buf][j * 512]);
        }
    };

    stage(0, 0);

    for (int it = 0; it < nkv; ++it) {
        const int cur = it & 1;
        if (it + 1 < nkv) {
            stage(it + 1, cur ^ 1);                     // 8 DMAs in flight
            asm volatile("s_waitcnt vmcnt(8)" ::: "memory");
        } else {
            asm volatile("s_waitcnt vmcnt(0)" ::: "memory");
        }

        // ---- K fragments: swizzled ds_read_b128, conflict-free ----
        const unsigned short* Kb = &KS[cur][0];
        const int rx = l31 & 7;
        short8 kf[4];
        #pragma unroll
        for (int c = 0; c < 4; ++c) {
            const int slot = (c * 2 + hi) ^ rx;
            kf[c] = *(const short8*)(Kb + l31 * 64 + slot * 8);
        }
        // ---- S^T = K . Q^T (32 kv-rows x 32 q-rows) ----
        f32x16 s0 = fzero16();
        __builtin_amdgcn_s_setprio(1);
        #pragma unroll
        for (int c = 0; c < 4; ++c)
            s0 = __builtin_amdgcn_mfma_f32_32x32x16_bf16(kf[c], fq[c], s0, 0, 0, 0);
        __builtin_amdgcn_s_setprio(0);
        // ---- causal mask: only the diagonal tile; predicate is STATIC ----
        if (bottom && it == qt) {
            #pragma unroll
            for (int r = 0; r < 16; ++r) {
                const int kk = (r & 3) + 8 * (r >> 2) + 4 * hi;
                if (kk > l31) s0[r] = -1e30f;
            }
        }
        // ---- max tree ----
        float tm[8];
        #pragma unroll
        for (int r = 0; r < 8; ++r) tm[r] = fmaxf(s0[r], s0[r + 8]);
        #pragma unroll
        for (int st = 4; st > 0; st >>= 1)
            #pragma unroll
            for (int r = 0; r < 4; ++r)
                if (r < st) tm[r] = fmaxf(tm[r], tm[r + st]);
        float pm = fmaxf(tm[0], __shfl_xor(tm[0], 32));
        // ---- T13 defer-rescale ----
        if (!__all(pm - mrun <= 8.f)) {
            const float mnew = fmaxf(mrun, pm);
            const float corr = exp2v(mrun - mnew);
            mrun = mnew;
            lrun *= corr;
            #pragma unroll
            for (int i = 0; i < 16; ++i) { o0[i] *= corr; o1[i] *= corr; }
        }
        float rs = 0.f;
        #pragma unroll
        for (int r = 0; r < 16; ++r) { s0[r] = exp2v(s0[r] - mrun); rs += s0[r]; }
        rs += __shfl_xor(rs, 32);
        lrun += rs;
        // ---- P -> bf16 B-frags (cvt_pk + xor32), PV accumulate ----
        const unsigned short* Vb = &VS[cur][0];
        unsigned pw[8], px[8];
        #pragma unroll
        for (int i = 0; i < 8; ++i)
            pw[i] = pkbf16(s0[2 * i], s0[2 * i + 1]);
        #pragma unroll
        for (int i = 0; i < 8; ++i)
            px[i] = (unsigned)__shfl_xor((int)pw[i], 32);
        __builtin_amdgcn_s_setprio(1);
        #pragma unroll
        for (int j = 0; j < 2; ++j) {   // k-chunk j*16
            short8 fp = hi ? mk8(px[j*4+2], px[j*4+3], pw[j*4+2], pw[j*4+3])
                           : mk8(pw[j*4+0], pw[j*4+1], px[j*4+0], px[j*4+1]);
            const int slot = j * 2 + hi;
            const int r0_ = l31, r1_ = 32 + l31;
            short8 v0 = *(const short8*)(Vb + r0_ * 32 + ((slot ^ (r0_ & 3)) * 8));
            short8 v1 = *(const short8*)(Vb + r1_ * 32 + ((slot ^ (r1_ & 3)) * 8));
            o0 = __builtin_amdgcn_mfma_f32_32x32x16_bf16(v0, fp, o0, 0, 0, 0);
            o1 = __builtin_amdgcn_mfma_f32_32x32x16_bf16(v1, fp, o1, 0, 0, 0);
        }
        __builtin_amdgcn_s_setprio(0);
    }

    // ---- epilogue: normalize, bounce O^T through LDS (single wave, no bar) --
    const float inv = 1.f / lrun;
    unsigned short* obuf = (unsigned short*)&KS[0][0];   // [32][72] shorts
    {
        unsigned short* reg = obuf + (size_t)l31 * 72;
        #pragma unroll
        for (int r = 0; r < 16; ++r) {
            const int dd = (r & 3) + 8 * (r >> 2) + 4 * hi;
            reg[dd]      = f2bf(o0[r] * inv);
            reg[dd + 32] = f2bf(o1[r] * inv);
        }
    }
    {
        const int row = l >> 1, seg = l & 1;
        const unsigned short* src = obuf + (size_t)row * 72 + seg * 32;
        unsigned short* dst = Og + (rb0 + qb + row) * DM + hd + seg * 32;
        #pragma unroll
        for (int i = 0; i < 4; ++i)
            *(short8*)(dst + i * 8) = *(const short8*)(src + i * 8);
    }
}

// ---------------------------------------------------------------------------
extern "C" void kernel_launch(void* const* d_in, const int* in_sizes, int n_in,
                              void* d_out, int out_size, void* d_ws, size_t ws_size,
                              hipStream_t stream)
{
    const float* x  = (const float*)d_in[0];
    const float* Wq = (const float*)d_in[1];
    const float* bq = (const float*)d_in[2];
    const float* Wk = (const float*)d_in[3];
    const float* bk = (const float*)d_in[4];
    const float* Wv = (const float*)d_in[5];
    const float* bv = (const float*)d_in[6];
    const float* Wo = (const float*)d_in[7];
    float* out = (float*)d_out;

    char* ws = (char*)d_ws;
    const size_t szA = (size_t)MROWS * DM * 2;   // 8.39 MB
    const size_t szW = (size_t)DM * DM * 2;      // 2.10 MB
    unsigned short* xb  = (unsigned short*)(ws);
    unsigned short* wqT = (unsigned short*)(ws + szA);            // wq/wk/wv/wo contiguous
    unsigned short* woT = (unsigned short*)(ws + szA + 3 * szW);
    unsigned short* qb_ = (unsigned short*)(ws + szA + 4 * szW);  // q/k/vt contiguous
    unsigned short* kb_ = (unsigned short*)(ws + 2 * szA + 4 * szW);
    unsigned short* vt_ = (unsigned short*)(ws + 3 * szA + 4 * szW);  // Vt[bh][d][n]
    unsigned short* ab_ = (unsigned short*)(ws + 4 * szA + 4 * szW);

    cvt_x<<<dim3(MROWS * DM / 8 / 256), 256, 0, stream>>>(x, xb, MROWS * DM / 8);
    cvt_w4<<<dim3(16, 16, 4), 256, 0, stream>>>(Wq, Wk, Wv, Wo, wqT);

    gemm_qkv<<<dim3(24, 32), 256, 0, stream>>>(xb, wqT, bq, bk, bv, qb_);
    attn_wave<<<dim3(2048), 64, 0, stream>>>(qb_, kb_, vt_, ab_);
    gemm_wo<<<dim3(8, 64), 256, 0, stream>>>(ab_, woT, out);
}

// Round 9
// 126.046 us; speedup vs baseline: 1.0984x; 1.0984x over previous
//
#include <hip/hip_runtime.h>
#include <hip/hip_bf16.h>

#define NH 16
#define DH 64
#define DM 1024
#define NC 2048
#define MROWS 4096
#define KVT 64

#define SCALE_Q 0.180336880f   // 0.125 * log2(e): softmax done in 2^x domain

typedef __attribute__((ext_vector_type(8))) short short8;
typedef __attribute__((ext_vector_type(4))) float f32x4;
typedef __attribute__((ext_vector_type(16))) float f32x16;
typedef __attribute__((ext_vector_type(4))) unsigned int uint4e;

__device__ __forceinline__ unsigned pkbf16(float a, float b) {
    unsigned r;
    asm("v_cvt_pk_bf16_f32 %0, %1, %2" : "=v"(r) : "v"(a), "v"(b));
    return r;
}
__device__ __forceinline__ unsigned short f2bf(float x) {
    return (unsigned short)(pkbf16(x, x) & 0xffffu);
}
__device__ __forceinline__ float exp2v(float x) {   // 2^x, v_exp_f32
    float r;
    asm("v_exp_f32 %0, %1" : "=v"(r) : "v"(x));
    return r;
}
__device__ __forceinline__ f32x16 fzero16() {
    f32x16 r;
    #pragma unroll
    for (int i = 0; i < 16; ++i) r[i] = 0.f;
    return r;
}
__device__ __forceinline__ short8 mk8(unsigned w0, unsigned w1, unsigned w2, unsigned w3) {
    uint4e u = {w0, w1, w2, w3};
    return __builtin_bit_cast(short8, u);
}
// async global->LDS, 16B per lane; lds dest = wave-uniform base + lane*16 (HW)
__device__ __forceinline__ void gload16(const unsigned short* g, unsigned short* l) {
    __builtin_amdgcn_global_load_lds(
        (const __attribute__((address_space(1))) void*)g,
        (__attribute__((address_space(3))) void*)l, 16, 0, 0);
}

// ---------------------------------------------------------------------------
// fp32 -> bf16 elementwise convert (8 elems/thread)
// ---------------------------------------------------------------------------
__global__ __launch_bounds__(256) void cvt_x(const float* __restrict__ in,
                                             unsigned short* __restrict__ out, int n8)
{
    int i = blockIdx.x * 256 + threadIdx.x;
    if (i >= n8) return;
    const float4 a = ((const float4*)in)[i * 2];
    const float4 b = ((const float4*)in)[i * 2 + 1];
    uint4e u = {pkbf16(a.x, a.y), pkbf16(a.z, a.w), pkbf16(b.x, b.y), pkbf16(b.z, b.w)};
    ((uint4e*)out)[i] = u;
}

// ---------------------------------------------------------------------------
// All 4 weights: W[K][N] fp32 -> Wt[N][K] bf16, fused (blockIdx.z = which W)
// ---------------------------------------------------------------------------
__global__ __launch_bounds__(256) void cvt_w4(const float* __restrict__ W0,
                                              const float* __restrict__ W1,
                                              const float* __restrict__ W2,
                                              const float* __restrict__ W3,
                                              unsigned short* __restrict__ Wt4)
{
    __shared__ unsigned short T[64][72];
    const int z = blockIdx.z;
    const float* W = (z == 0) ? W0 : (z == 1) ? W1 : (z == 2) ? W2 : W3;
    unsigned short* Wt = Wt4 + (size_t)z * DM * DM;
    const int t = threadIdx.x;
    const int r = t >> 2, s = t & 3;
    const int bi = blockIdx.y;
    const int bj = blockIdx.x;
    const float* src = W + (size_t)(bi * 64 + r) * DM + bj * 64 + s * 16;
    float4 f0 = ((const float4*)src)[0];
    float4 f1 = ((const float4*)src)[1];
    float4 f2 = ((const float4*)src)[2];
    float4 f3 = ((const float4*)src)[3];
    uint2 u;
    u.x = pkbf16(f0.x, f0.y); u.y = pkbf16(f0.z, f0.w); *(uint2*)&T[r][s * 16]      = u;
    u.x = pkbf16(f1.x, f1.y); u.y = pkbf16(f1.z, f1.w); *(uint2*)&T[r][s * 16 + 4]  = u;
    u.x = pkbf16(f2.x, f2.y); u.y = pkbf16(f2.z, f2.w); *(uint2*)&T[r][s * 16 + 8]  = u;
    u.x = pkbf16(f3.x, f3.y); u.y = pkbf16(f3.z, f3.w); *(uint2*)&T[r][s * 16 + 12] = u;
    __syncthreads();
    unsigned short vals[16];
    #pragma unroll
    for (int j = 0; j < 16; ++j) vals[j] = T[s * 16 + j][r];
    unsigned short* dst = Wt + (size_t)(bj * 64 + r) * DM + bi * 64 + s * 16;
    *(short8*)(dst)     = *(short8*)&vals[0];
    *(short8*)(dst + 8) = *(short8*)&vals[8];
}

// ---------------------------------------------------------------------------
// Fused QKV projection (m97 structure): 128x128 tile, BK=32, 4 waves,
// global_load_lds width-16 staging into LINEAR LDS [128][32] shorts.
// Q pre-scaled by SCALE_Q. V segment written TRANSPOSED to Vt[bh][d][n].
// ---------------------------------------------------------------------------
__global__ __launch_bounds__(256) void gemm_qkv(const unsigned short* __restrict__ A,
                                                const unsigned short* __restrict__ Bt,
                                                const float* __restrict__ bq,
                                                const float* __restrict__ bk,
                                                const float* __restrict__ bv,
                                                unsigned short* __restrict__ Out)
{
    __shared__ unsigned short As[128 * 32];
    __shared__ unsigned short Bs[128 * 32];
    const int t  = threadIdx.x;
    const int w  = t >> 6, l = t & 63;
    const int wr = w >> 1, wc = w & 1;
    const int m0 = blockIdx.y << 7;
    const int n0 = blockIdx.x << 7;

    f32x4 acc[4][4] = {};
    const int nkt = DM >> 5;
    for (int kt = 0; kt < nkt; ++kt) {
        #pragma unroll
        for (int j = 0; j < 2; ++j) {
            const int c0 = j * 256 + w * 64;          // wave-uniform chunk base
            const int cc = c0 + l;                    // per-lane chunk
            const int row = cc >> 2, qq = cc & 3;
            gload16(A  + (size_t)(m0 + row) * DM + kt * 32 + qq * 8, &As[c0 * 8]);
            gload16(Bt + (size_t)(n0 + row) * DM + kt * 32 + qq * 8, &Bs[c0 * 8]);
        }
        __syncthreads();
        short8 af[4], bf_[4];
        #pragma unroll
        for (int mi = 0; mi < 4; ++mi)
            af[mi] = *(short8*)&As[(wr * 64 + mi * 16 + (l & 15)) * 32 + (l >> 4) * 8];
        #pragma unroll
        for (int ni = 0; ni < 4; ++ni)
            bf_[ni] = *(short8*)&Bs[(wc * 64 + ni * 16 + (l & 15)) * 32 + (l >> 4) * 8];
        #pragma unroll
        for (int mi = 0; mi < 4; ++mi)
            #pragma unroll
            for (int ni = 0; ni < 4; ++ni)
                acc[mi][ni] = __builtin_amdgcn_mfma_f32_16x16x32_bf16(
                                  af[mi], bf_[ni], acc[mi][ni], 0, 0, 0);
        __syncthreads();
    }

    const int seg = n0 >> 10;
    const float* bias = (seg == 0) ? bq : (seg == 1) ? bk : bv;
    const float scale = (seg == 0) ? SCALE_Q : 1.0f;
    const int ncol0 = (n0 & 1023) + wc * 64;
    float bvv[4];
    #pragma unroll
    for (int ni = 0; ni < 4; ++ni)
        bvv[ni] = bias[ncol0 + ni * 16 + (l & 15)];

    if (seg == 2) {
        // V: write transposed Vt[bh][d][n] (bh = b*16+h)
        unsigned short* vt = Out + 2 * (size_t)MROWS * DM;
        #pragma unroll
        for (int mi = 0; mi < 4; ++mi)
            #pragma unroll
            for (int ni = 0; ni < 4; ++ni) {
                const int gcol = ncol0 + ni * 16 + (l & 15);
                const int h_ = gcol >> 6, d_ = gcol & 63;
                #pragma unroll
                for (int r = 0; r < 4; ++r) {
                    const int grow = m0 + wr * 64 + mi * 16 + (l >> 4) * 4 + r;
                    const int b_ = grow >> 11, n_ = grow & 2047;
                    vt[(((size_t)b_ * 16 + h_) * 64 + d_) * NC + n_] =
                        f2bf(acc[mi][ni][r] + bvv[ni]);
                }
            }
    } else {
        unsigned short* C = Out + (size_t)seg * MROWS * DM;
        #pragma unroll
        for (int mi = 0; mi < 4; ++mi)
            #pragma unroll
            for (int ni = 0; ni < 4; ++ni) {
                const int gcol = ncol0 + ni * 16 + (l & 15);
                #pragma unroll
                for (int r = 0; r < 4; ++r) {
                    const int grow = m0 + wr * 64 + mi * 16 + (l >> 4) * 4 + r;
                    C[(size_t)grow * DM + gcol] = f2bf((acc[mi][ni][r] + bvv[ni]) * scale);
                }
            }
    }
}

// ---------------------------------------------------------------------------
// Output projection: 64x128 tile, gload_lds staging, fp32 out.
// ---------------------------------------------------------------------------
__global__ __launch_bounds__(256) void gemm_wo(const unsigned short* __restrict__ A,
                                               const unsigned short* __restrict__ Bt,
                                               float* __restrict__ C)
{
    __shared__ unsigned short As[64 * 32];
    __shared__ unsigned short Bs[128 * 32];
    const int t = threadIdx.x, w = t >> 6, l = t & 63;
    const int wr = w >> 1, wc = w & 1;
    const int m0 = blockIdx.y << 6;
    const int n0 = blockIdx.x << 7;

    f32x4 acc[2][4] = {};
    const int nkt = DM >> 5;
    for (int kt = 0; kt < nkt; ++kt) {
        {
            const int c0 = w * 64;
            const int cc = c0 + l;
            const int row = cc >> 2, qq = cc & 3;
            gload16(A + (size_t)(m0 + row) * DM + kt * 32 + qq * 8, &As[c0 * 8]);
        }
        #pragma unroll
        for (int j = 0; j < 2; ++j) {
            const int c0 = j * 256 + w * 64;
            const int cc = c0 + l;
            const int row = cc >> 2, qq = cc & 3;
            gload16(Bt + (size_t)(n0 + row) * DM + kt * 32 + qq * 8, &Bs[c0 * 8]);
        }
        __syncthreads();
        short8 af[2], bf_[4];
        #pragma unroll
        for (int mi = 0; mi < 2; ++mi)
            af[mi] = *(short8*)&As[(wr * 32 + mi * 16 + (l & 15)) * 32 + (l >> 4) * 8];
        #pragma unroll
        for (int ni = 0; ni < 4; ++ni)
            bf_[ni] = *(short8*)&Bs[(wc * 64 + ni * 16 + (l & 15)) * 32 + (l >> 4) * 8];
        #pragma unroll
        for (int mi = 0; mi < 2; ++mi)
            #pragma unroll
            for (int ni = 0; ni < 4; ++ni)
                acc[mi][ni] = __builtin_amdgcn_mfma_f32_16x16x32_bf16(
                                  af[mi], bf_[ni], acc[mi][ni], 0, 0, 0);
        __syncthreads();
    }
    #pragma unroll
    for (int mi = 0; mi < 2; ++mi)
        #pragma unroll
        for (int ni = 0; ni < 4; ++ni) {
            const int gcol = n0 + wc * 64 + ni * 16 + (l & 15);
            #pragma unroll
            for (int r = 0; r < 4; ++r) {
                const int grow = m0 + wr * 32 + mi * 16 + (l >> 4) * 4 + r;
                C[(size_t)grow * DM + gcol] = acc[mi][ni][r];
            }
        }
}

// ---------------------------------------------------------------------------
// Wave-independent flash attention, SINGLE-buffered K/V + read-early-to-regs.
// 1 wave/block, 2048 blocks, KVT=64, LDS 16KB -> 8 resident blocks/CU.
// Per iter: vmcnt(0) [DMAs issued a full iter ago -> ~free] -> ds_read all
// K/V frags to regs -> lgkmcnt(0) -> issue next tile's 16 DMAs into the SAME
// buffers -> QK (2 independent chains) -> softmax (tree-sum) -> PV from regs.
// Zero barriers. K/V tiles [64][128B], slot^=(row&7) swizzle (2-way = free).
// ---------------------------------------------------------------------------
__global__ __launch_bounds__(64, 2) void attn_sb(const unsigned short* __restrict__ Qg,
                                                 const unsigned short* __restrict__ Kg,
                                                 const unsigned short* __restrict__ Vtg,
                                                 unsigned short* __restrict__ Og)
{
    __shared__ unsigned short KS[4096];   // [64 rows][8 slots x 8 shorts]
    __shared__ unsigned short VS[4096];   // [64 d-rows][8 slots x 8 shorts]
    const int l   = threadIdx.x;
    const int l31 = l & 31;
    const int hi  = l >> 5;

    // T1 XCD-chunked swizzle: 2048 blocks, 8 XCDs -> 4 (b,h) x 64 q-tiles each
    const int f   = blockIdx.x;
    const int xcd = f & 7;
    const int pos = f >> 3;               // 0..255
    const int bh  = xcd * 4 + (pos >> 6);
    int qt = pos & 63;
    if ((pos >> 6) & 1) qt = 63 - qt;     // long/short causal pairing
    const int b = bh >> 4;
    const int h = bh & 15;

    const int qb = qt << 5;               // 32 q-rows per wave
    const size_t rb0 = (size_t)b * NC;
    const int hd = h * DH;

    // Q fragments (pre-scaled by 0.125*log2e in projection)
    const unsigned short* qp = Qg + (rb0 + qb + l31) * DM + hd + hi * 8;
    short8 fq[4];
    #pragma unroll
    for (int c = 0; c < 4; ++c)
        fq[c] = *(const short8*)(qp + c * 16);

    f32x16 o0 = fzero16(), o1 = fzero16();
    float mrun = -1e30f, lrun = 0.f;
    const bool bottom = (qb >= NC / 2);   // qt >= 32
    const int nkv = bottom ? ((qt >> 1) + 1) : 16;

    const unsigned short* Vbase = Vtg + (size_t)bh * 64 * NC;

    // stage one KVT=64 tile: 8 K-DMA + 8 V-DMA, inverse swizzle on source
    auto stage = [&](int it) {
        const int kb = it * KVT;
        #pragma unroll
        for (int j = 0; j < 8; ++j) {
            const int p    = j * 64 + l;              // chunk 0..511
            const int row  = p >> 3;                  // 0..63
            const int slot = (p & 7) ^ (row & 7);
            gload16(Kg + (size_t)(rb0 + kb + row) * DM + hd + slot * 8,
                    &KS[j * 512]);
            gload16(Vbase + (size_t)row * NC + kb + slot * 8,
                    &VS[j * 512]);
        }
    };

    stage(0);

    for (int it = 0; it < nkv; ++it) {
        const int kb = it * KVT;
        // DMAs for this tile were issued one full iteration ago -> short wait
        asm volatile("s_waitcnt vmcnt(0)" ::: "memory");

        // ---- read ALL K/V fragments to registers (swizzled, 2-way free) ----
        short8 kf[2][4], vf[2][4];
        #pragma unroll
        for (int half = 0; half < 2; ++half) {
            const int row = half * 32 + l31;
            const int rx  = row & 7;
            #pragma unroll
            for (int c = 0; c < 4; ++c) {
                const int slot = (c * 2 + hi) ^ rx;
                kf[half][c] = *(const short8*)(&KS[row * 64 + slot * 8]);
                vf[half][c] = *(const short8*)(&VS[row * 64 + slot * 8]);
            }
        }
        asm volatile("s_waitcnt lgkmcnt(0)" ::: "memory");
        __builtin_amdgcn_sched_barrier(0);
        // ---- now safe to overwrite the buffers: issue next tile's DMAs ----
        if (it + 1 < nkv) stage(it + 1);

        // ---- S^T = K . Q^T : two independent accumulation chains ----
        f32x16 s0 = fzero16(), s1 = fzero16();
        __builtin_amdgcn_s_setprio(1);
        #pragma unroll
        for (int c = 0; c < 4; ++c) {
            s0 = __builtin_amdgcn_mfma_f32_32x32x16_bf16(kf[0][c], fq[c], s0, 0, 0, 0);
            s1 = __builtin_amdgcn_mfma_f32_32x32x16_bf16(kf[1][c], fq[c], s1, 0, 0, 0);
        }
        __builtin_amdgcn_s_setprio(0);

        // ---- causal mask: only the last (diagonal-crossing) tile ----
        if (bottom && it == nkv - 1) {
            const int qg = qb + l31;
            #pragma unroll
            for (int r = 0; r < 16; ++r) {
                const int kk = (r & 3) + 8 * (r >> 2) + 4 * hi;
                if (kb + kk > qg)      s0[r] = -1e30f;
                if (kb + 32 + kk > qg) s1[r] = -1e30f;
            }
        }
        // ---- max tree ----
        float tm[16];
        #pragma unroll
        for (int r = 0; r < 16; ++r) tm[r] = fmaxf(s0[r], s1[r]);
        #pragma unroll
        for (int st = 8; st > 0; st >>= 1)
            #pragma unroll
            for (int r = 0; r < 8; ++r)
                if (r < st) tm[r] = fmaxf(tm[r], tm[r + st]);
        float pm = fmaxf(tm[0], __shfl_xor(tm[0], 32));
        // ---- T13 defer-rescale ----
        if (!__all(pm - mrun <= 8.f)) {
            const float mnew = fmaxf(mrun, pm);
            const float corr = exp2v(mrun - mnew);
            mrun = mnew;
            lrun *= corr;
            #pragma unroll
            for (int i = 0; i < 16; ++i) { o0[i] *= corr; o1[i] *= corr; }
        }
        // ---- exp (parallel) + pairwise tree-sum (short dependency) ----
        #pragma unroll
        for (int r = 0; r < 16; ++r) s0[r] = exp2v(s0[r] - mrun);
        #pragma unroll
        for (int r = 0; r < 16; ++r) s1[r] = exp2v(s1[r] - mrun);
        float t16[16];
        #pragma unroll
        for (int r = 0; r < 16; ++r) t16[r] = s0[r] + s1[r];
        #pragma unroll
        for (int st = 8; st > 0; st >>= 1)
            #pragma unroll
            for (int r = 0; r < 8; ++r)
                if (r < st) t16[r] += t16[r + st];
        lrun += t16[0] + __shfl_xor(t16[0], 32);

        // ---- P -> bf16 B-frags (cvt_pk + xor32), PV from REGISTERS ----
        __builtin_amdgcn_s_setprio(1);
        #pragma unroll
        for (int kc = 0; kc < 4; ++kc) {
            const f32x16 src = (kc < 2) ? s0 : s1;
            const int rbase = (kc & 1) * 8;
            unsigned A01 = pkbf16(src[rbase + 0], src[rbase + 1]);
            unsigned A23 = pkbf16(src[rbase + 2], src[rbase + 3]);
            unsigned A45 = pkbf16(src[rbase + 4], src[rbase + 5]);
            unsigned A67 = pkbf16(src[rbase + 6], src[rbase + 7]);
            unsigned s01 = (unsigned)__shfl_xor((int)A01, 32);
            unsigned s23 = (unsigned)__shfl_xor((int)A23, 32);
            unsigned s45 = (unsigned)__shfl_xor((int)A45, 32);
            unsigned s67 = (unsigned)__shfl_xor((int)A67, 32);
            short8 fp = hi ? mk8(s45, s67, A45, A67)
                           : mk8(A01, A23, s01, s23);
            o0 = __builtin_amdgcn_mfma_f32_32x32x16_bf16(vf[0][kc], fp, o0, 0, 0, 0);
            o1 = __builtin_amdgcn_mfma_f32_32x32x16_bf16(vf[1][kc], fp, o1, 0, 0, 0);
        }
        __builtin_amdgcn_s_setprio(0);
    }

    // ---- epilogue: normalize, bounce O^T through LDS (single wave) ----
    const float inv = 1.f / lrun;
    unsigned short* obuf = &KS[0];   // [32][72] shorts
    {
        unsigned short* reg = obuf + (size_t)l31 * 72;
        #pragma unroll
        for (int r = 0; r < 16; ++r) {
            const int dd = (r & 3) + 8 * (r >> 2) + 4 * hi;
            reg[dd]      = f2bf(o0[r] * inv);
            reg[dd + 32] = f2bf(o1[r] * inv);
        }
    }
    {
        const int row = l >> 1, seg = l & 1;
        const unsigned short* src = obuf + (size_t)row * 72 + seg * 32;
        unsigned short* dst = Og + (rb0 + qb + row) * DM + hd + seg * 32;
        #pragma unroll
        for (int i = 0; i < 4; ++i)
            *(short8*)(dst + i * 8) = *(const short8*)(src + i * 8);
    }
}

// ---------------------------------------------------------------------------
extern "C" void kernel_launch(void* const* d_in, const int* in_sizes, int n_in,
                              void* d_out, int out_size, void* d_ws, size_t ws_size,
                              hipStream_t stream)
{
    const float* x  = (const float*)d_in[0];
    const float* Wq = (const float*)d_in[1];
    const float* bq = (const float*)d_in[2];
    const float* Wk = (const float*)d_in[3];
    const float* bk = (const float*)d_in[4];
    const float* Wv = (const float*)d_in[5];
    const float* bv = (const float*)d_in[6];
    const float* Wo = (const float*)d_in[7];
    float* out = (float*)d_out;

    char* ws = (char*)d_ws;
    const size_t szA = (size_t)MROWS * DM * 2;   // 8.39 MB
    const size_t szW = (size_t)DM * DM * 2;      // 2.10 MB
    unsigned short* xb  = (unsigned short*)(ws);
    unsigned short* wqT = (unsigned short*)(ws + szA);            // wq/wk/wv/wo contiguous
    unsigned short* woT = (unsigned short*)(ws + szA + 3 * szW);
    unsigned short* qb_ = (unsigned short*)(ws + szA + 4 * szW);  // q/k/vt contiguous
    unsigned short* kb_ = (unsigned short*)(ws + 2 * szA + 4 * szW);
    unsigned short* vt_ = (unsigned short*)(ws + 3 * szA + 4 * szW);  // Vt[bh][d][n]
    unsigned short* ab_ = (unsigned short*)(ws + 4 * szA + 4 * szW);

    cvt_x<<<dim3(MROWS * DM / 8 / 256), 256, 0, stream>>>(x, xb, MROWS * DM / 8);
    cvt_w4<<<dim3(16, 16, 4), 256, 0, stream>>>(Wq, Wk, Wv, Wo, wqT);

    gemm_qkv<<<dim3(24, 32), 256, 0, stream>>>(xb, wqT, bq, bk, bv, qb_);
    attn_sb<<<dim3(2048), 64, 0, stream>>>(qb_, kb_, vt_, ab_);
    gemm_wo<<<dim3(8, 64), 256, 0, stream>>>(ab_, woT, out);
}